// Round 4
// baseline (884.373 us; speedup 1.0000x reference)
//
#include <hip/hip_runtime.h>
#include <cstdint>

// ---------------------------------------------------------------------------
// GatedCrossAttention  (E=1024, Z=256, L=2048, B=8)
// No-LDS "flatmm": BOTH GEMM operands pre-shuffled into MFMA fragment order;
// every operand load is one coalesced global_load_dwordx4 direct to VGPRs.
// No barriers anywhere in the GEMM -> no vmcnt(0) drain; compiler emits
// fine-grained waitcnts around the register double-buffer.
// ---------------------------------------------------------------------------

#define EN 1024
#define ZN 256
#define LN_ 2048
#define BN_ 8
#define MROWS (LN_ * BN_)          // 16384
#define QRU_N (2 * EN + ZN)        // 2304
#define LEN_SCALE 0.022097086912079608f  // 1/sqrt(2048)

typedef unsigned short u16;
typedef __bf16 bf16x8 __attribute__((ext_vector_type(8)));
typedef float f32x4 __attribute__((ext_vector_type(4)));

// ---- bf16 helpers ---------------------------------------------------------
__device__ __forceinline__ u16 f2bf(float f) {
    unsigned int u = __float_as_uint(f);
    u = (u + 0x7fff + ((u >> 16) & 1)) >> 16;
    return (u16)u;
}
__device__ __forceinline__ float bf2f(u16 s) {
    return __uint_as_float(((unsigned int)s) << 16);
}

// ---------------------------------------------------------------------------
// Canonical fragment-shuffle. For an operand with KC = K/32 k-chunks:
// element (row, col) lives at chunk (row>>4)*KC + (col>>5), lane
// (row&15)|(((col>>3)&3)<<4), byte-octet j = col&7.  This matches the
// mfma_f32_16x16x32_bf16 A/B fragment map (row=lane&15, k=(lane>>4)*8+j),
// verified by rounds 1-2 passing with this exact read pattern via LDS.
// ---------------------------------------------------------------------------
__device__ __forceinline__ long long shuf(int row, int col, int KC) {
    return ((long long)((row >> 4) * KC + (col >> 5)) << 9)
         + (((row & 15) | (((col >> 3) & 3) << 4)) << 3) + (col & 7);
}

// ---------------------------------------------------------------------------
// GEMM-FF: C[M,N] = A[M,K] @ B[N,K]^T, both operands fragment-shuffled bf16.
// Block 256 = 4 waves (2x2), block tile 128x128, each wave 64x64.
// Register double-buffer over k-chunks; no LDS, no synchronization.
// ---------------------------------------------------------------------------
template <int K, typename Epi>
__global__ __launch_bounds__(256, 3)
void gemm_ff(const u16* __restrict__ A, const u16* __restrict__ B,
             long long sA, long long sB, Epi epi)
{
    constexpr int KC = K / 32;
    const int lane = threadIdx.x & 63;
    const int w    = threadIdx.x >> 6;
    const int wm = w >> 1, wn = w & 1;
    const int bz = blockIdx.z;
    const int mt0 = blockIdx.y * 8 + wm * 4;   // base m-tile (16 rows each)
    const int nt0 = blockIdx.x * 8 + wn * 4;   // base n-tile
    const u16* Ap = A + bz * sA + ((long long)mt0 * KC) * 512 + lane * 8;
    const u16* Bp = B + bz * sB + ((long long)nt0 * KC) * 512 + lane * 8;

    const f32x4 fzero = {0.f, 0.f, 0.f, 0.f};
    f32x4 acc[4][4];
#pragma unroll
    for (int i = 0; i < 4; ++i)
#pragma unroll
        for (int j = 0; j < 4; ++j) acc[i][j] = fzero;

    bf16x8 af[2][4], bf[2][4];
#pragma unroll
    for (int i = 0; i < 4; ++i) {
        af[0][i] = *(const bf16x8*)(Ap + (i * KC) * 512);
        bf[0][i] = *(const bf16x8*)(Bp + (i * KC) * 512);
    }

#pragma unroll 2
    for (int kc = 0; kc < KC; ++kc) {
        const int cur = kc & 1, nxt = cur ^ 1;
        if (kc + 1 < KC) {
#pragma unroll
            for (int i = 0; i < 4; ++i) {
                af[nxt][i] = *(const bf16x8*)(Ap + (i * KC + kc + 1) * 512);
                bf[nxt][i] = *(const bf16x8*)(Bp + (i * KC + kc + 1) * 512);
            }
        }
#pragma unroll
        for (int mi = 0; mi < 4; ++mi)
#pragma unroll
            for (int ni = 0; ni < 4; ++ni)
                acc[mi][ni] = __builtin_amdgcn_mfma_f32_16x16x32_bf16(
                    af[cur][mi], bf[cur][ni], acc[mi][ni], 0, 0, 0);
    }

    // epilogue: D[row][col], col = lane&15, row = quad*4 + reg  [m89/m91]
    const int quad = lane >> 4, l16 = lane & 15;
#pragma unroll
    for (int mi = 0; mi < 4; ++mi)
#pragma unroll
        for (int ni = 0; ni < 4; ++ni)
#pragma unroll
            for (int r = 0; r < 4; ++r) {
                int m = (mt0 + mi) * 16 + quad * 4 + r;
                int n = (nt0 + ni) * 16 + l16;
                epi(bz, m, n, acc[mi][ni][r]);
            }
}

// ---- epilogue functors -----------------------------------------------------
struct EpiRaw {            // kraw = key@Wk^T + bk   -> fp32 (16384 x 256)
    float* out; const float* bias;
    __device__ void operator()(int, int m, int n, float v) const {
        out[(long long)m * ZN + n] = v + bias[n];
    }
};
struct EpiQru {            // base = nq@Wqru^T + bqru; split q-raw / u / r
    float* qraw; u16* u; u16* r; const float* bqru;
    __device__ void operator()(int, int m, int n, float v) const {
        v += bqru[n];
        if (n < ZN) {
            qraw[(long long)m * ZN + n] = v;
        } else if (n < ZN + EN) {
            float s = 1.f / (1.f + __expf(-v));
            u[(long long)m * EN + (n - ZN)] = f2bf(s);
        } else {
            float s = v / (1.f + __expf(-v));
            r[(long long)m * EN + (n - ZN - EN)] = f2bf(s);
        }
    }
};
struct EpiV {              // v = silu(value@Wv^T + bv) -> shuffled (row=e,col=c)
    u16* v; const float* bv;
    __device__ void operator()(int, int m, int n, float acc) const {
        float x = acc + bv[n];
        float s = x / (1.f + __expf(-x));
        int b = m & 7, c = m >> 3;
        v[(long long)b * (EN * LN_) + shuf(n, c, LN_ / 32)] = f2bf(s);
    }
};
struct EpiQK {             // attn = relu(qk*scale+bias)^2 -> shuffled (row=s,col=c)
    u16* attn; const float* relpos;
    __device__ void operator()(int bz, int m, int n, float v) const {
        float val = v * LEN_SCALE + relpos[2047 + n - m];
        float t = fmaxf(val, 0.f);
        attn[(long long)bz * (LN_ * LN_) + shuf(m, n, LN_ / 32)] = f2bf(t * t);
    }
};
struct EpiH {              // hr = (attn@v)*r -> shuffled (row=s*8+b, col=e)
    u16* hr; const u16* r;
    __device__ void operator()(int bz, int m, int n, float acc) const {
        int row = m * BN_ + bz;
        float rv = bf2f(r[(long long)row * EN + n]);
        hr[shuf(row, n, EN / 32)] = f2bf(acc * rv);
    }
};
struct EpiOut {            // out = query + u*((hr@Wh^T + bh) - query), fp32
    float* out; const float* query; const u16* u; const float* bh;
    __device__ void operator()(int, int m, int n, float acc) const {
        long long idx = (long long)m * EN + n;
        float qv = query[idx];
        float uu = bf2f(u[idx]);
        out[idx] = qv + uu * ((acc + bh[n]) - qv);
    }
};

// ---------------------------------------------------------------------------
// prep: LN(query)->nq; cast key_in, value -> bf16. All written fragment-
// shuffled over (row=m, col=e, KC=32).  1 block per row; e = tid*4 keeps the
// 4 elements inside one lane-octet (e&7 in {0,4}) -> single 8B store each.
// ---------------------------------------------------------------------------
__global__ __launch_bounds__(256)
void prep_kernel(const float* __restrict__ query, const float* __restrict__ key_in,
                 const float* __restrict__ value, const float* __restrict__ ln_w,
                 const float* __restrict__ ln_b,
                 u16* __restrict__ nq, u16* __restrict__ kin, u16* __restrict__ val)
{
    __shared__ float r1[4], r2[4];
    const int m = blockIdx.x, t = threadIdx.x;
    const long long base = (long long)m * EN + t * 4;
    float4 q = *(const float4*)(query + base);
    float a1 = q.x + q.y + q.z + q.w;
    float a2 = q.x * q.x + q.y * q.y + q.z * q.z + q.w * q.w;
#pragma unroll
    for (int o = 32; o; o >>= 1) { a1 += __shfl_down(a1, o, 64); a2 += __shfl_down(a2, o, 64); }
    if ((t & 63) == 0) { r1[t >> 6] = a1; r2[t >> 6] = a2; }
    __syncthreads();
    const float S1 = r1[0] + r1[1] + r1[2] + r1[3];
    const float S2 = r2[0] + r2[1] + r2[2] + r2[3];
    const float mu = S1 * (1.f / EN);
    const float var = S2 * (1.f / EN) - mu * mu;
    const float rstd = rsqrtf(var + 1e-5f);
    const int e = t * 4;
    float4 wv = *(const float4*)(ln_w + e);
    float4 bv = *(const float4*)(ln_b + e);
    const long long o = shuf(m, e, EN / 32);
    union { u16 h[4]; uint2 v2; } pk;
    pk.h[0] = f2bf((q.x - mu) * rstd * wv.x + bv.x);
    pk.h[1] = f2bf((q.y - mu) * rstd * wv.y + bv.y);
    pk.h[2] = f2bf((q.z - mu) * rstd * wv.z + bv.z);
    pk.h[3] = f2bf((q.w - mu) * rstd * wv.w + bv.w);
    *(uint2*)(nq + o) = pk.v2;
    float4 kq = *(const float4*)(key_in + base);
    pk.h[0] = f2bf(kq.x); pk.h[1] = f2bf(kq.y); pk.h[2] = f2bf(kq.z); pk.h[3] = f2bf(kq.w);
    *(uint2*)(kin + o) = pk.v2;
    float4 vq = *(const float4*)(value + base);
    pk.h[0] = f2bf(vq.x); pk.h[1] = f2bf(vq.y); pk.h[2] = f2bf(vq.z); pk.h[3] = f2bf(vq.w);
    *(uint2*)(val + o) = pk.v2;
}

// ---------------------------------------------------------------------------
// l2norm over Z=256 + scale/shift; writes fragment-shuffled (row, col=z, KC=8)
// per batch.  raw rows are m = s*8+b; output row = s within batch b.
// ---------------------------------------------------------------------------
__global__ __launch_bounds__(256)
void l2norm_scale(const float* __restrict__ raw, u16* __restrict__ out,
                  const float* __restrict__ gamma, const float* __restrict__ beta)
{
    __shared__ float red[4];
    const int m = blockIdx.x, z = threadIdx.x;
    const float x = raw[(long long)m * ZN + z];
    float ss = x * x;
#pragma unroll
    for (int o = 32; o; o >>= 1) ss += __shfl_down(ss, o, 64);
    if ((z & 63) == 0) red[z >> 6] = ss;
    __syncthreads();
    const float tot = red[0] + red[1] + red[2] + red[3];
    const float inv = 1.f / fmaxf(sqrtf(tot), 1e-5f);
    const float res = x * inv * (gamma[z] + 1.f) + beta[z];
    const int b = m & 7, s = m >> 3;
    out[(long long)b * (LN_ * ZN) + shuf(s, z, ZN / 32)] = f2bf(res);
}

// ---------------------------------------------------------------------------
// weight shuffle-cast: W fp32 (N x K) -> fragment-ordered bf16 (1 wave/chunk)
// ---------------------------------------------------------------------------
__global__ __launch_bounds__(256)
void shuffle_castw(const float* __restrict__ W, u16* __restrict__ out, int KC)
{
    const int chunk = blockIdx.x * 4 + (threadIdx.x >> 6);
    const int lane  = threadIdx.x & 63;
    const int nt = chunk / KC, kc = chunk - nt * KC;
    const int n = nt * 16 + (lane & 15);
    const int k = kc * 32 + (lane >> 4) * 8;
    const float* src = W + (long long)n * (KC * 32) + k;
    float4 a = *(const float4*)src;
    float4 b = *(const float4*)(src + 4);
    union { u16 h[8]; uint4 v; } pk;
    pk.h[0] = f2bf(a.x); pk.h[1] = f2bf(a.y); pk.h[2] = f2bf(a.z); pk.h[3] = f2bf(a.w);
    pk.h[4] = f2bf(b.x); pk.h[5] = f2bf(b.y); pk.h[6] = f2bf(b.z); pk.h[7] = f2bf(b.w);
    *(uint4*)(out + (long long)chunk * 512 + lane * 8) = pk.v;
}

// ---------------------------------------------------------------------------
extern "C" void kernel_launch(void* const* d_in, const int* in_sizes, int n_in,
                              void* d_out, int out_size, void* d_ws, size_t ws_size,
                              hipStream_t stream)
{
    const float* query  = (const float*)d_in[0];
    const float* key_in = (const float*)d_in[1];
    const float* value  = (const float*)d_in[2];
    const float* ln_w   = (const float*)d_in[3];
    const float* ln_b   = (const float*)d_in[4];
    const float* Wv     = (const float*)d_in[5];
    const float* bv     = (const float*)d_in[6];
    const float* Wk     = (const float*)d_in[7];
    const float* bk     = (const float*)d_in[8];
    const float* Wqru   = (const float*)d_in[9];
    const float* bqru   = (const float*)d_in[10];
    const float* Wh     = (const float*)d_in[11];
    const float* bh     = (const float*)d_in[12];
    const float* gamma  = (const float*)d_in[13];
    const float* beta   = (const float*)d_in[14];
    const float* relpos = (const float*)d_in[15];
    float* out = (float*)d_out;

    char* ws = (char*)d_ws;
    const size_t MB = 1ull << 20;
    u16*   nq    = (u16*)(ws + 0);          // 32 MiB shuffled, dead after GEMM-qru
    u16*   kin   = (u16*)(ws + 32 * MB);    // 32 MiB shuffled, dead after GEMM-k
    u16*   attn  = (u16*)(ws + 0);          // 64 MiB shuffled (aliases nq+kin)
    u16*   valb  = (u16*)(ws + 64 * MB);    // 32 MiB shuffled, dead after GEMM-v
    u16*   hr    = (u16*)(ws + 64 * MB);    // 32 MiB shuffled (aliases valb)
    u16*   qb    = (u16*)(ws + 96 * MB);    // 8 MiB  shuffled per batch
    u16*   kb    = (u16*)(ws + 104 * MB);   // 8 MiB  shuffled per batch
    u16*   ub    = (u16*)(ws + 112 * MB);   // 32 MiB row-major
    u16*   rb    = (u16*)(ws + 144 * MB);   // 32 MiB row-major
    u16*   vSh   = (u16*)(ws + 176 * MB);   // 32 MiB shuffled per batch
    float* raw   = (float*)(ws + 208 * MB); // 16 MiB (kraw then qraw)
    u16*   WqruB = (u16*)(ws + 224 * MB);   // 4.5 MiB (shuffled)
    u16*   WkB   = (u16*)(ws + 229 * MB);   // 0.5 MiB
    u16*   WvB   = (u16*)(ws + 230 * MB);   // 2 MiB
    u16*   WhB   = (u16*)(ws + 232 * MB);   // 2 MiB   (total 234 MiB)
    (void)ws_size; (void)in_sizes; (void)n_in; (void)out_size;

    // 1) shuffle-cast weights to fragment-ordered bf16
    shuffle_castw<<<dim3((QRU_N / 16) * (EN / 32) / 4), 256, 0, stream>>>(Wqru, WqruB, EN / 32);
    shuffle_castw<<<dim3((ZN / 16) * (EN / 32) / 4), 256, 0, stream>>>(Wk, WkB, EN / 32);
    shuffle_castw<<<dim3((EN / 16) * (EN / 32) / 4), 256, 0, stream>>>(Wv, WvB, EN / 32);
    shuffle_castw<<<dim3((EN / 16) * (EN / 32) / 4), 256, 0, stream>>>(Wh, WhB, EN / 32);

    // 2) layernorm(query) + bf16 casts of key/value (all fragment-shuffled)
    prep_kernel<<<dim3(MROWS), 256, 0, stream>>>(query, key_in, value, ln_w, ln_b, nq, kin, valb);

    // 3) k = l2norm(key@Wk^T + bk)*g1 + beta1  -> kb (shuffled per batch)
    gemm_ff<EN><<<dim3(ZN / 128, MROWS / 128, 1), 256, 0, stream>>>(
        kin, WkB, 0LL, 0LL, EpiRaw{raw, bk});
    l2norm_scale<<<dim3(MROWS), 256, 0, stream>>>(raw, kb, gamma + ZN, beta + ZN);

    // 4) base = nq@Wqru^T + bqru -> qraw / u / r;  qb shuffled per batch
    gemm_ff<EN><<<dim3(QRU_N / 128, MROWS / 128, 1), 256, 0, stream>>>(
        nq, WqruB, 0LL, 0LL, EpiQru{raw, ub, rb, bqru});
    l2norm_scale<<<dim3(MROWS), 256, 0, stream>>>(raw, qb, gamma, beta);

    // 5) v = silu(value@Wv^T + bv) -> vSh (shuffled, row=e col=c per batch)
    gemm_ff<EN><<<dim3(EN / 128, MROWS / 128, 1), 256, 0, stream>>>(
        valb, WvB, 0LL, 0LL, EpiV{vSh, bv});

    // 6) attn = relu(q@k^T * scale + bias)^2   (batched over b)
    gemm_ff<ZN><<<dim3(LN_ / 128, LN_ / 128, BN_), 256, 0, stream>>>(
        qb, kb, (long long)LN_ * ZN, (long long)LN_ * ZN, EpiQK{attn, relpos});

    // 7) hr = (attn @ v) * r   (batched over b)
    gemm_ff<LN_><<<dim3(EN / 128, LN_ / 128, BN_), 256, 0, stream>>>(
        attn, vSh, (long long)LN_ * LN_, (long long)EN * LN_, EpiH{hr, rb});

    // 8) out = query + u*((hr@Wh^T + bh) - query)
    gemm_ff<EN><<<dim3(EN / 128, MROWS / 128, 1), 256, 0, stream>>>(
        hr, WhB, 0LL, 0LL, EpiOut{out, query, ub, bh});
}